// Round 1
// baseline (409.966 us; speedup 1.0000x reference)
//
#include <hip/hip_runtime.h>
#include <hip/hip_bf16.h>

typedef __bf16 bf16;
typedef __bf16 bf16x8 __attribute__((ext_vector_type(8)));
typedef float f32x4 __attribute__((ext_vector_type(4)));

// Problem constants
#define BB 2
#define TT 4096
#define CC 512
#define HH 8
#define HD 64
#define BHD 16          // B*H
#define M_TOT 8192      // B*T

// ---------------------------------------------------------------------------
// GEMM 1: qkv = x @ w_qkv   [8192,512] x [512,1536] -> scatter q/k/v bf16
// block tile 128x128, 4 waves, each wave 64x64 (4x4 frags of 16x16), BK=32
// ---------------------------------------------------------------------------
__global__ __launch_bounds__(256) void gemm_qkv_kernel(
    const float* __restrict__ X, const float* __restrict__ W,
    bf16* __restrict__ qw, bf16* __restrict__ kw, bf16* __restrict__ vw) {
  __shared__ __align__(16) bf16 As[128 * 40];
  __shared__ __align__(16) bf16 Bs[128 * 40];   // transposed: [n][k]
  const int tid = threadIdx.x;
  const int wid = tid >> 6, lane = tid & 63, ln = lane & 15, hi = lane >> 4;
  const int wr = wid >> 1, wc = wid & 1;
  const int m0 = blockIdx.x * 128, n0 = blockIdx.y * 128;

  f32x4 acc[4][4] = {};

  for (int k0 = 0; k0 < 512; k0 += 32) {
    __syncthreads();
    // stage A: rows m0..m0+127, cols k0..k0+31, convert f32->bf16
#pragma unroll
    for (int it = 0; it < 2; ++it) {
      int ch = tid + it * 256;          // 512 chunks of 8
      int r = ch >> 2, c8 = ch & 3;
      const float4* p = (const float4*)(X + (size_t)(m0 + r) * 512 + k0 + c8 * 8);
      float4 a = p[0], b = p[1];
      bf16x8 v;
      v[0] = (bf16)a.x; v[1] = (bf16)a.y; v[2] = (bf16)a.z; v[3] = (bf16)a.w;
      v[4] = (bf16)b.x; v[5] = (bf16)b.y; v[6] = (bf16)b.z; v[7] = (bf16)b.w;
      *(bf16x8*)&As[r * 40 + c8 * 8] = v;
    }
    // stage B transposed: Bs[n][k] = W[k0+k][n0+n]
#pragma unroll
    for (int it = 0; it < 2; ++it) {
      int ch = tid + it * 256;          // 32 rows x 16 chunks
      int r = ch >> 4, c8 = ch & 15;
      const float4* p = (const float4*)(W + (size_t)(k0 + r) * 1536 + n0 + c8 * 8);
      float4 a = p[0], b = p[1];
      float vals[8] = {a.x, a.y, a.z, a.w, b.x, b.y, b.z, b.w};
#pragma unroll
      for (int j = 0; j < 8; ++j) Bs[(c8 * 8 + j) * 40 + r] = (bf16)vals[j];
    }
    __syncthreads();

    bf16x8 af[4], bfr[4];
#pragma unroll
    for (int mi = 0; mi < 4; ++mi)
      af[mi] = *(const bf16x8*)&As[(wr * 64 + mi * 16 + ln) * 40 + hi * 8];
#pragma unroll
    for (int ni = 0; ni < 4; ++ni)
      bfr[ni] = *(const bf16x8*)&Bs[(wc * 64 + ni * 16 + ln) * 40 + hi * 8];
#pragma unroll
    for (int mi = 0; mi < 4; ++mi)
#pragma unroll
      for (int ni = 0; ni < 4; ++ni)
        acc[mi][ni] = __builtin_amdgcn_mfma_f32_16x16x32_bf16(af[mi], bfr[ni], acc[mi][ni], 0, 0, 0);
  }

  // epilogue: D col = lane&15, row = (lane>>4)*4 + reg  -> scatter to [bh][t][d]
#pragma unroll
  for (int mi = 0; mi < 4; ++mi) {
    int rowb = m0 + wr * 64 + mi * 16 + hi * 4;
#pragma unroll
    for (int ni = 0; ni < 4; ++ni) {
      int n = n0 + wc * 64 + ni * 16 + ln;
      int which = n >> 9, c = n & 511, h = c >> 6, d = c & 63;
      bf16* dst = (which == 0) ? qw : (which == 1) ? kw : vw;
#pragma unroll
      for (int r = 0; r < 4; ++r) {
        int m = rowb + r;
        int b = m >> 12, t = m & 4095;
        dst[((size_t)(b * HH + h) * TT + t) * HD + d] = (bf16)acc[mi][ni][r];
      }
    }
  }
}

// ---------------------------------------------------------------------------
// Flash attention, causal. grid = (T/64, BH). 4 waves, 16 q-rows each.
// ---------------------------------------------------------------------------
__global__ __launch_bounds__(256) void attn_kernel(
    const bf16* __restrict__ qw, const bf16* __restrict__ kw,
    const bf16* __restrict__ vw, bf16* __restrict__ aw) {
  __shared__ __align__(16) bf16 Ks[64 * 72];        // [kv][d]
  __shared__ __align__(16) bf16 Vt[64 * 72];        // [d][kv]
  __shared__ __align__(16) bf16 Ps[4][16 * 72];     // per wave [q][kv]
  const int tid = threadIdx.x;
  const int wid = tid >> 6, lane = tid & 63, ln = lane & 15, hi = lane >> 4;
  const int qb = blockIdx.x, bh = blockIdx.y;
  const int q0 = qb * 64 + wid * 16;

  // Q fragments in registers: A[row=ln][k = half*32 + hi*8 + j]
  bf16x8 qf[2];
#pragma unroll
  for (int h = 0; h < 2; ++h)
    qf[h] = *(const bf16x8*)&qw[((size_t)bh * TT + q0 + ln) * HD + h * 32 + hi * 8];

  f32x4 o[4] = {};
  float mrow[4], lrow[4];
#pragma unroll
  for (int r = 0; r < 4; ++r) { mrow[r] = -1e30f; lrow[r] = 0.f; }

  const int ntiles = qb + 1;
  for (int t = 0; t < ntiles; ++t) {
    const int kv0 = t * 64;
    __syncthreads();
#pragma unroll
    for (int it = 0; it < 2; ++it) {
      int ch = tid + it * 256;       // 64 rows x 8 chunks of 8
      int r = ch >> 3, c = (ch & 7) * 8;
      const size_t src = ((size_t)bh * TT + kv0 + r) * HD + c;
      *(bf16x8*)&Ks[r * 72 + c] = *(const bf16x8*)&kw[src];
      bf16x8 v = *(const bf16x8*)&vw[src];
#pragma unroll
      for (int j = 0; j < 8; ++j) Vt[(c + j) * 72 + r] = v[j];
    }
    __syncthreads();

    // S = (Q K^T) * scale ; D layout: col(ln)=kv, row(hi*4+r)=q
    f32x4 s[4];
#pragma unroll
    for (int kt = 0; kt < 4; ++kt) {
      f32x4 a = {};
#pragma unroll
      for (int h = 0; h < 2; ++h) {
        bf16x8 kf = *(const bf16x8*)&Ks[(kt * 16 + ln) * 72 + h * 32 + hi * 8];
        a = __builtin_amdgcn_mfma_f32_16x16x32_bf16(qf[h], kf, a, 0, 0, 0);
      }
      s[kt] = a * 0.125f;
    }
    if (t == ntiles - 1) {
#pragma unroll
      for (int kt = 0; kt < 4; ++kt)
#pragma unroll
        for (int r = 0; r < 4; ++r) {
          int kg = kv0 + kt * 16 + ln, qg = q0 + hi * 4 + r;
          if (kg > qg) s[kt][r] = -1e30f;
        }
    }
    // online softmax (rows spread: lanes with same hi hold one row's 16 cols)
    float tmax[4];
#pragma unroll
    for (int r = 0; r < 4; ++r) {
      float v = fmaxf(fmaxf(s[0][r], s[1][r]), fmaxf(s[2][r], s[3][r]));
#pragma unroll
      for (int msk = 1; msk < 16; msk <<= 1) v = fmaxf(v, __shfl_xor(v, msk, 16));
      tmax[r] = v;
    }
    float alpha[4], rsum[4];
#pragma unroll
    for (int r = 0; r < 4; ++r) {
      float mn = fmaxf(mrow[r], tmax[r]);
      alpha[r] = __expf(mrow[r] - mn);
      mrow[r] = mn;
      rsum[r] = 0.f;
    }
#pragma unroll
    for (int kt = 0; kt < 4; ++kt)
#pragma unroll
      for (int r = 0; r < 4; ++r) {
        float p = __expf(s[kt][r] - mrow[r]);
        rsum[r] += p;
        Ps[wid][(hi * 4 + r) * 72 + kt * 16 + ln] = (bf16)p;
      }
#pragma unroll
    for (int r = 0; r < 4; ++r) {
      float v = rsum[r];
#pragma unroll
      for (int msk = 1; msk < 16; msk <<= 1) v += __shfl_xor(v, msk, 16);
      lrow[r] = lrow[r] * alpha[r] + v;
    }
#pragma unroll
    for (int db = 0; db < 4; ++db)
#pragma unroll
      for (int r = 0; r < 4; ++r) o[db][r] *= alpha[r];
    // PV: A=P [q=ln][kv], B=V [kv][d=ln via Vt]
#pragma unroll
    for (int db = 0; db < 4; ++db) {
#pragma unroll
      for (int h = 0; h < 2; ++h) {
        bf16x8 pf = *(const bf16x8*)&Ps[wid][ln * 72 + h * 32 + hi * 8];
        bf16x8 vf = *(const bf16x8*)&Vt[(db * 16 + ln) * 72 + h * 32 + hi * 8];
        o[db] = __builtin_amdgcn_mfma_f32_16x16x32_bf16(pf, vf, o[db], 0, 0, 0);
      }
    }
  }

#pragma unroll
  for (int db = 0; db < 4; ++db)
#pragma unroll
    for (int r = 0; r < 4; ++r) {
      int q = q0 + hi * 4 + r;
      aw[((size_t)bh * TT + q) * HD + db * 16 + ln] = (bf16)(o[db][r] / lrow[r]);
    }
}

// ---------------------------------------------------------------------------
// GEMM 3: out = attn @ w_out   [8192,512] x [512,512] -> f32 out
// A gathered from [bh][t][d] bf16 layout.
// ---------------------------------------------------------------------------
__global__ __launch_bounds__(256) void gemm_out_kernel(
    const bf16* __restrict__ A, const float* __restrict__ W,
    float* __restrict__ out) {
  __shared__ __align__(16) bf16 As[128 * 40];
  __shared__ __align__(16) bf16 Bs[128 * 40];
  const int tid = threadIdx.x;
  const int wid = tid >> 6, lane = tid & 63, ln = lane & 15, hi = lane >> 4;
  const int wr = wid >> 1, wc = wid & 1;
  const int m0 = blockIdx.x * 128, n0 = blockIdx.y * 128;

  f32x4 acc[4][4] = {};

  for (int k0 = 0; k0 < 512; k0 += 32) {
    __syncthreads();
#pragma unroll
    for (int it = 0; it < 2; ++it) {
      int ch = tid + it * 256;
      int r = ch >> 2, c8 = ch & 3;
      int m = m0 + r, k = k0 + c8 * 8;
      int b = m >> 12, t = m & 4095, h = k >> 6, d = k & 63;
      *(bf16x8*)&As[r * 40 + c8 * 8] =
          *(const bf16x8*)&A[((size_t)(b * HH + h) * TT + t) * HD + d];
    }
#pragma unroll
    for (int it = 0; it < 2; ++it) {
      int ch = tid + it * 256;
      int r = ch >> 4, c8 = ch & 15;
      const float4* p = (const float4*)(W + (size_t)(k0 + r) * 512 + n0 + c8 * 8);
      float4 a = p[0], b = p[1];
      float vals[8] = {a.x, a.y, a.z, a.w, b.x, b.y, b.z, b.w};
#pragma unroll
      for (int j = 0; j < 8; ++j) Bs[(c8 * 8 + j) * 40 + r] = (bf16)vals[j];
    }
    __syncthreads();

    bf16x8 af[4], bfr[4];
#pragma unroll
    for (int mi = 0; mi < 4; ++mi)
      af[mi] = *(const bf16x8*)&As[(wr * 64 + mi * 16 + ln) * 40 + hi * 8];
#pragma unroll
    for (int ni = 0; ni < 4; ++ni)
      bfr[ni] = *(const bf16x8*)&Bs[(wc * 64 + ni * 16 + ln) * 40 + hi * 8];
#pragma unroll
    for (int mi = 0; mi < 4; ++mi)
#pragma unroll
      for (int ni = 0; ni < 4; ++ni)
        acc[mi][ni] = __builtin_amdgcn_mfma_f32_16x16x32_bf16(af[mi], bfr[ni], acc[mi][ni], 0, 0, 0);
  }

#pragma unroll
  for (int mi = 0; mi < 4; ++mi) {
    int rowb = m0 + wr * 64 + mi * 16 + hi * 4;
#pragma unroll
    for (int ni = 0; ni < 4; ++ni) {
      int n = n0 + wc * 64 + ni * 16 + ln;
#pragma unroll
      for (int r = 0; r < 4; ++r)
        out[(size_t)(rowb + r) * 512 + n] = acc[mi][ni][r];
    }
  }
}

extern "C" void kernel_launch(void* const* d_in, const int* in_sizes, int n_in,
                              void* d_out, int out_size, void* d_ws, size_t ws_size,
                              hipStream_t stream) {
  const float* x = (const float*)d_in[0];
  const float* w_qkv = (const float*)d_in[1];
  const float* w_out = (const float*)d_in[2];
  float* out = (float*)d_out;

  const size_t QKV_ELEMS = (size_t)BHD * TT * HD;   // 4,194,304
  bf16* qw = (bf16*)d_ws;
  bf16* kw = qw + QKV_ELEMS;
  bf16* vw = kw + QKV_ELEMS;
  bf16* aw = vw + QKV_ELEMS;

  gemm_qkv_kernel<<<dim3(M_TOT / 128, 1536 / 128), 256, 0, stream>>>(x, w_qkv, qw, kw, vw);
  attn_kernel<<<dim3(TT / 64, BHD), 256, 0, stream>>>(qw, kw, vw, aw);
  gemm_out_kernel<<<dim3(M_TOT / 128, 512 / 128), 256, 0, stream>>>(aw, w_out, out);
}

// Round 2
// 249.969 us; speedup vs baseline: 1.6401x; 1.6401x over previous
//
#include <hip/hip_runtime.h>
#include <hip/hip_bf16.h>

typedef __bf16 bf16;
typedef __bf16 bf16x4 __attribute__((ext_vector_type(4)));
typedef __bf16 bf16x8 __attribute__((ext_vector_type(8)));
typedef float f32x4 __attribute__((ext_vector_type(4)));

// Problem constants
#define BB 2
#define TT 4096
#define CC 512
#define HH 8
#define HD 64
#define BHD 16          // B*H
#define M_TOT 8192      // B*T

// ---------------------------------------------------------------------------
// GEMM 1: qkv = x @ w_qkv   [8192,512] x [512,1536] -> scatter q/k bf16
// [bh][t][d]; v transposed to [bh][d][t] for conflict-free attn staging.
// ---------------------------------------------------------------------------
__global__ __launch_bounds__(256) void gemm_qkv_kernel(
    const float* __restrict__ X, const float* __restrict__ W,
    bf16* __restrict__ qw, bf16* __restrict__ kw, bf16* __restrict__ vw) {
  __shared__ __align__(16) bf16 As[128 * 40];
  __shared__ __align__(16) bf16 Bs[128 * 40];   // transposed: [n][k]
  const int tid = threadIdx.x;
  const int wid = tid >> 6, lane = tid & 63, ln = lane & 15, hi = lane >> 4;
  const int wr = wid >> 1, wc = wid & 1;
  const int m0 = blockIdx.x * 128, n0 = blockIdx.y * 128;

  f32x4 acc[4][4] = {};

  for (int k0 = 0; k0 < 512; k0 += 32) {
    __syncthreads();
#pragma unroll
    for (int it = 0; it < 2; ++it) {
      int ch = tid + it * 256;          // 512 chunks of 8
      int r = ch >> 2, c8 = ch & 3;
      const float4* p = (const float4*)(X + (size_t)(m0 + r) * 512 + k0 + c8 * 8);
      float4 a = p[0], b = p[1];
      bf16x8 v;
      v[0] = (bf16)a.x; v[1] = (bf16)a.y; v[2] = (bf16)a.z; v[3] = (bf16)a.w;
      v[4] = (bf16)b.x; v[5] = (bf16)b.y; v[6] = (bf16)b.z; v[7] = (bf16)b.w;
      *(bf16x8*)&As[r * 40 + c8 * 8] = v;
    }
#pragma unroll
    for (int it = 0; it < 2; ++it) {
      int ch = tid + it * 256;          // 32 rows x 16 chunks
      int r = ch >> 4, c8 = ch & 15;
      const float4* p = (const float4*)(W + (size_t)(k0 + r) * 1536 + n0 + c8 * 8);
      float4 a = p[0], b = p[1];
      float vals[8] = {a.x, a.y, a.z, a.w, b.x, b.y, b.z, b.w};
#pragma unroll
      for (int j = 0; j < 8; ++j) Bs[(c8 * 8 + j) * 40 + r] = (bf16)vals[j];
    }
    __syncthreads();

    bf16x8 af[4], bfr[4];
#pragma unroll
    for (int mi = 0; mi < 4; ++mi)
      af[mi] = *(const bf16x8*)&As[(wr * 64 + mi * 16 + ln) * 40 + hi * 8];
#pragma unroll
    for (int ni = 0; ni < 4; ++ni)
      bfr[ni] = *(const bf16x8*)&Bs[(wc * 64 + ni * 16 + ln) * 40 + hi * 8];
#pragma unroll
    for (int mi = 0; mi < 4; ++mi)
#pragma unroll
      for (int ni = 0; ni < 4; ++ni)
        acc[mi][ni] = __builtin_amdgcn_mfma_f32_16x16x32_bf16(af[mi], bfr[ni], acc[mi][ni], 0, 0, 0);
  }

  // D: col = lane&15, row = (lane>>4)*4 + reg
#pragma unroll
  for (int mi = 0; mi < 4; ++mi) {
    int rowb = m0 + wr * 64 + mi * 16 + hi * 4;
    int b = rowb >> 12, t0 = rowb & 4095;
#pragma unroll
    for (int ni = 0; ni < 4; ++ni) {
      int n = n0 + wc * 64 + ni * 16 + ln;
      int which = n >> 9, c = n & 511, h = c >> 6, d = c & 63;
      if (which == 2) {
        // v -> [bh][d][t], 4 consecutive t => one 8B store
        bf16x4 pv;
#pragma unroll
        for (int r = 0; r < 4; ++r) pv[r] = (bf16)acc[mi][ni][r];
        *(bf16x4*)&vw[((size_t)(b * HH + h) * HD + d) * TT + t0] = pv;
      } else {
        bf16* dst = which ? kw : qw;
#pragma unroll
        for (int r = 0; r < 4; ++r)
          dst[((size_t)(b * HH + h) * TT + t0 + r) * HD + d] = (bf16)acc[mi][ni][r];
      }
    }
  }
}

// ---------------------------------------------------------------------------
// Flash attention, causal. 1D grid 512 (work-paired). 4 waves x 32 q-rows.
// K: [kv][d] LDS (XOR-swizzled); V: [d][kv] LDS from pre-transposed global;
// P: per-wave LDS round-trip (swizzled). Async-stage split (T14).
// ---------------------------------------------------------------------------
__global__ __launch_bounds__(256) void attn_kernel(
    const bf16* __restrict__ qw, const bf16* __restrict__ kw,
    const bf16* __restrict__ vt, bf16* __restrict__ aw) {
  __shared__ __align__(16) bf16 Ks[64 * 64];
  __shared__ __align__(16) bf16 Vs[64 * 64];        // [d][kv]
  __shared__ __align__(16) bf16 Ps[4][32 * 64];     // per wave [q][kv]
  const int tid = threadIdx.x;
  const int wid = tid >> 6, lane = tid & 63, ln = lane & 15, hi = lane >> 4;

  // pair blocks: half 0 -> qb = p, half 1 -> qb = 31-p (constant work per pair)
  const int bid = blockIdx.x;
  const int half = bid >> 8, rem = bid & 255;
  const int bh = rem >> 4, p = rem & 15;
  const int qb = half ? (31 - p) : p;
  const int q0w = qb * 128 + wid * 32;

  // Q fragments (A-frag): row = ln, k = h*32 + hi*8 + j
  bf16x8 qf[2][2];
#pragma unroll
  for (int qi = 0; qi < 2; ++qi)
#pragma unroll
    for (int h = 0; h < 2; ++h)
      qf[qi][h] = *(const bf16x8*)&qw[((size_t)bh * TT + q0w + qi * 16 + ln) * HD + h * 32 + hi * 8];

  f32x4 o[2][4] = {};
  float mrow[2][4], lrow[2][4];
#pragma unroll
  for (int qi = 0; qi < 2; ++qi)
#pragma unroll
    for (int r = 0; r < 4; ++r) { mrow[qi][r] = -1e30f; lrow[qi][r] = 0.f; }

  const int ntiles = 2 * (qb + 1);
  const int r0 = tid >> 3, c0 = tid & 7;    // staging row/chunk
  const int sc = (c0 ^ (r0 & 7)) * 8;       // swizzled chunk offset (r0+32 same)

  bf16x8 pre[4];
  {
    const size_t kb = (size_t)bh * TT * HD, vb = (size_t)bh * HD * TT;
    pre[0] = *(const bf16x8*)&kw[kb + (size_t)r0 * HD + c0 * 8];
    pre[1] = *(const bf16x8*)&kw[kb + (size_t)(r0 + 32) * HD + c0 * 8];
    pre[2] = *(const bf16x8*)&vt[vb + (size_t)r0 * TT + c0 * 8];
    pre[3] = *(const bf16x8*)&vt[vb + (size_t)(r0 + 32) * TT + c0 * 8];
  }

  for (int t = 0; t < ntiles; ++t) {
    const int kv0 = t * 64;
    __syncthreads();
    *(bf16x8*)&Ks[r0 * 64 + sc] = pre[0];
    *(bf16x8*)&Ks[(r0 + 32) * 64 + sc] = pre[1];
    *(bf16x8*)&Vs[r0 * 64 + sc] = pre[2];
    *(bf16x8*)&Vs[(r0 + 32) * 64 + sc] = pre[3];
    if (t + 1 < ntiles) {   // issue next tile early; lands under compute
      const int kv1 = kv0 + 64;
      const size_t kb = (size_t)bh * TT * HD, vb = (size_t)bh * HD * TT;
      pre[0] = *(const bf16x8*)&kw[kb + (size_t)(kv1 + r0) * HD + c0 * 8];
      pre[1] = *(const bf16x8*)&kw[kb + (size_t)(kv1 + r0 + 32) * HD + c0 * 8];
      pre[2] = *(const bf16x8*)&vt[vb + (size_t)r0 * TT + kv1 + c0 * 8];
      pre[3] = *(const bf16x8*)&vt[vb + (size_t)(r0 + 32) * TT + kv1 + c0 * 8];
    }
    __syncthreads();
    if (kv0 > q0w + 31) continue;   // wave fully above diagonal: skip compute

    // QK^T: D col(ln)=kv, row(hi*4+r)=q
    f32x4 s[2][4];
#pragma unroll
    for (int kt = 0; kt < 4; ++kt) {
      const int krow = kt * 16 + ln;
      bf16x8 kf0 = *(const bf16x8*)&Ks[krow * 64 + ((hi ^ (krow & 7)) * 8)];
      bf16x8 kf1 = *(const bf16x8*)&Ks[krow * 64 + (((4 + hi) ^ (krow & 7)) * 8)];
#pragma unroll
      for (int qi = 0; qi < 2; ++qi) {
        f32x4 a = {};
        a = __builtin_amdgcn_mfma_f32_16x16x32_bf16(qf[qi][0], kf0, a, 0, 0, 0);
        a = __builtin_amdgcn_mfma_f32_16x16x32_bf16(qf[qi][1], kf1, a, 0, 0, 0);
        s[qi][kt] = a * 0.125f;
      }
    }
    // causal mask (wave-uniform gate per qi)
#pragma unroll
    for (int qi = 0; qi < 2; ++qi) {
      if (kv0 + 63 > q0w + qi * 16) {
#pragma unroll
        for (int kt = 0; kt < 4; ++kt)
#pragma unroll
          for (int r = 0; r < 4; ++r) {
            int kg = kv0 + kt * 16 + ln, qg = q0w + qi * 16 + hi * 4 + r;
            if (kg > qg) s[qi][kt][r] = -1e30f;
          }
      }
    }
    // online softmax + P to per-wave LDS (swizzled)
#pragma unroll
    for (int qi = 0; qi < 2; ++qi) {
      float alpha[4], rsum[4];
#pragma unroll
      for (int r = 0; r < 4; ++r) {
        float v = fmaxf(fmaxf(s[qi][0][r], s[qi][1][r]), fmaxf(s[qi][2][r], s[qi][3][r]));
#pragma unroll
        for (int msk = 1; msk < 16; msk <<= 1) v = fmaxf(v, __shfl_xor(v, msk));
        float mn = fmaxf(mrow[qi][r], v);
        alpha[r] = __expf(mrow[qi][r] - mn);
        mrow[qi][r] = mn;
        rsum[r] = 0.f;
      }
#pragma unroll
      for (int kt = 0; kt < 4; ++kt)
#pragma unroll
        for (int r = 0; r < 4; ++r) {
          float pv = __expf(s[qi][kt][r] - mrow[qi][r]);
          rsum[r] += pv;
          int q_ = qi * 16 + hi * 4 + r;
          Ps[wid][q_ * 64 + ((kt * 16 + ln) ^ ((q_ & 7) << 3))] = (bf16)pv;
        }
#pragma unroll
      for (int r = 0; r < 4; ++r) {
        float v = rsum[r];
#pragma unroll
        for (int msk = 1; msk < 16; msk <<= 1) v += __shfl_xor(v, msk);
        lrow[qi][r] = lrow[qi][r] * alpha[r] + v;
      }
#pragma unroll
      for (int db = 0; db < 4; ++db)
#pragma unroll
        for (int r = 0; r < 4; ++r) o[qi][db][r] *= alpha[r];
    }
    // PV: A = P[q][kv] (own-wave LDS), B = V^T rows from Vs[d][kv]
#pragma unroll
    for (int qi = 0; qi < 2; ++qi) {
      const int prow = qi * 16 + ln;
      bf16x8 pf0 = *(const bf16x8*)&Ps[wid][prow * 64 + ((hi ^ (ln & 7)) * 8)];
      bf16x8 pf1 = *(const bf16x8*)&Ps[wid][prow * 64 + (((4 + hi) ^ (ln & 7)) * 8)];
#pragma unroll
      for (int db = 0; db < 4; ++db) {
        const int vrow = db * 16 + ln;
        bf16x8 vf0 = *(const bf16x8*)&Vs[vrow * 64 + ((hi ^ (ln & 7)) * 8)];
        bf16x8 vf1 = *(const bf16x8*)&Vs[vrow * 64 + (((4 + hi) ^ (ln & 7)) * 8)];
        o[qi][db] = __builtin_amdgcn_mfma_f32_16x16x32_bf16(pf0, vf0, o[qi][db], 0, 0, 0);
        o[qi][db] = __builtin_amdgcn_mfma_f32_16x16x32_bf16(pf1, vf1, o[qi][db], 0, 0, 0);
      }
    }
  }

#pragma unroll
  for (int qi = 0; qi < 2; ++qi)
#pragma unroll
    for (int db = 0; db < 4; ++db)
#pragma unroll
      for (int r = 0; r < 4; ++r) {
        int q = q0w + qi * 16 + hi * 4 + r;
        aw[((size_t)bh * TT + q) * HD + db * 16 + ln] = (bf16)(o[qi][db][r] / lrow[qi][r]);
      }
}

// ---------------------------------------------------------------------------
// GEMM 3: out = attn @ w_out   [8192,512] x [512,512] -> f32 out
// ---------------------------------------------------------------------------
__global__ __launch_bounds__(256) void gemm_out_kernel(
    const bf16* __restrict__ A, const float* __restrict__ W,
    float* __restrict__ out) {
  __shared__ __align__(16) bf16 As[128 * 40];
  __shared__ __align__(16) bf16 Bs[128 * 40];
  const int tid = threadIdx.x;
  const int wid = tid >> 6, lane = tid & 63, ln = lane & 15, hi = lane >> 4;
  const int wr = wid >> 1, wc = wid & 1;
  const int m0 = blockIdx.x * 128, n0 = blockIdx.y * 128;

  f32x4 acc[4][4] = {};

  for (int k0 = 0; k0 < 512; k0 += 32) {
    __syncthreads();
#pragma unroll
    for (int it = 0; it < 2; ++it) {
      int ch = tid + it * 256;
      int r = ch >> 2, c8 = ch & 3;
      int m = m0 + r, k = k0 + c8 * 8;
      int b = m >> 12, t = m & 4095, h = k >> 6, d = k & 63;
      *(bf16x8*)&As[r * 40 + c8 * 8] =
          *(const bf16x8*)&A[((size_t)(b * HH + h) * TT + t) * HD + d];
    }
#pragma unroll
    for (int it = 0; it < 2; ++it) {
      int ch = tid + it * 256;
      int r = ch >> 4, c8 = ch & 15;
      const float4* p = (const float4*)(W + (size_t)(k0 + r) * 512 + n0 + c8 * 8);
      float4 a = p[0], b = p[1];
      float vals[8] = {a.x, a.y, a.z, a.w, b.x, b.y, b.z, b.w};
#pragma unroll
      for (int j = 0; j < 8; ++j) Bs[(c8 * 8 + j) * 40 + r] = (bf16)vals[j];
    }
    __syncthreads();

    bf16x8 af[4], bfr[4];
#pragma unroll
    for (int mi = 0; mi < 4; ++mi)
      af[mi] = *(const bf16x8*)&As[(wr * 64 + mi * 16 + ln) * 40 + hi * 8];
#pragma unroll
    for (int ni = 0; ni < 4; ++ni)
      bfr[ni] = *(const bf16x8*)&Bs[(wc * 64 + ni * 16 + ln) * 40 + hi * 8];
#pragma unroll
    for (int mi = 0; mi < 4; ++mi)
#pragma unroll
      for (int ni = 0; ni < 4; ++ni)
        acc[mi][ni] = __builtin_amdgcn_mfma_f32_16x16x32_bf16(af[mi], bfr[ni], acc[mi][ni], 0, 0, 0);
  }

#pragma unroll
  for (int mi = 0; mi < 4; ++mi) {
    int rowb = m0 + wr * 64 + mi * 16 + hi * 4;
#pragma unroll
    for (int ni = 0; ni < 4; ++ni) {
      int n = n0 + wc * 64 + ni * 16 + ln;
#pragma unroll
      for (int r = 0; r < 4; ++r)
        out[(size_t)(rowb + r) * 512 + n] = acc[mi][ni][r];
    }
  }
}

extern "C" void kernel_launch(void* const* d_in, const int* in_sizes, int n_in,
                              void* d_out, int out_size, void* d_ws, size_t ws_size,
                              hipStream_t stream) {
  const float* x = (const float*)d_in[0];
  const float* w_qkv = (const float*)d_in[1];
  const float* w_out = (const float*)d_in[2];
  float* out = (float*)d_out;

  const size_t QKV_ELEMS = (size_t)BHD * TT * HD;   // 4,194,304
  bf16* qw = (bf16*)d_ws;
  bf16* kw = qw + QKV_ELEMS;
  bf16* vw = kw + QKV_ELEMS;   // transposed layout [bh][d][t]
  bf16* aw = vw + QKV_ELEMS;

  gemm_qkv_kernel<<<dim3(M_TOT / 128, 1536 / 128), 256, 0, stream>>>(x, w_qkv, qw, kw, vw);
  attn_kernel<<<512, 256, 0, stream>>>(qw, kw, vw, aw);
  gemm_out_kernel<<<dim3(M_TOT / 128, 512 / 128), 256, 0, stream>>>(aw, w_out, out);
}

// Round 3
// 216.872 us; speedup vs baseline: 1.8904x; 1.1526x over previous
//
#include <hip/hip_runtime.h>
#include <hip/hip_bf16.h>

typedef __bf16 bf16;
typedef __bf16 bf16x4 __attribute__((ext_vector_type(4)));
typedef __bf16 bf16x8 __attribute__((ext_vector_type(8)));
typedef float f32x4 __attribute__((ext_vector_type(4)));

// Problem constants
#define BB 2
#define TT 4096
#define CC 512
#define HH 8
#define HD 64
#define BHD 16          // B*H
#define M_TOT 8192      // B*T

// ---------------------------------------------------------------------------
// GEMM 1: qkv = x @ w_qkv   [8192,512] x [512,1536] -> scatter q/k bf16
// [bh][t][d]; v transposed to [bh][d][t] for conflict-free attn staging.
// ---------------------------------------------------------------------------
__global__ __launch_bounds__(256) void gemm_qkv_kernel(
    const float* __restrict__ X, const float* __restrict__ W,
    bf16* __restrict__ qw, bf16* __restrict__ kw, bf16* __restrict__ vw) {
  __shared__ __align__(16) bf16 As[128 * 40];
  __shared__ __align__(16) bf16 Bs[128 * 40];   // transposed: [n][k]
  const int tid = threadIdx.x;
  const int wid = tid >> 6, lane = tid & 63, ln = lane & 15, hi = lane >> 4;
  const int wr = wid >> 1, wc = wid & 1;
  const int m0 = blockIdx.x * 128, n0 = blockIdx.y * 128;

  f32x4 acc[4][4] = {};

  for (int k0 = 0; k0 < 512; k0 += 32) {
    __syncthreads();
#pragma unroll
    for (int it = 0; it < 2; ++it) {
      int ch = tid + it * 256;          // 512 chunks of 8
      int r = ch >> 2, c8 = ch & 3;
      const float4* p = (const float4*)(X + (size_t)(m0 + r) * 512 + k0 + c8 * 8);
      float4 a = p[0], b = p[1];
      bf16x8 v;
      v[0] = (bf16)a.x; v[1] = (bf16)a.y; v[2] = (bf16)a.z; v[3] = (bf16)a.w;
      v[4] = (bf16)b.x; v[5] = (bf16)b.y; v[6] = (bf16)b.z; v[7] = (bf16)b.w;
      *(bf16x8*)&As[r * 40 + c8 * 8] = v;
    }
#pragma unroll
    for (int it = 0; it < 2; ++it) {
      int ch = tid + it * 256;          // 32 rows x 16 chunks
      int r = ch >> 4, c8 = ch & 15;
      const float4* p = (const float4*)(W + (size_t)(k0 + r) * 1536 + n0 + c8 * 8);
      float4 a = p[0], b = p[1];
      float vals[8] = {a.x, a.y, a.z, a.w, b.x, b.y, b.z, b.w};
#pragma unroll
      for (int j = 0; j < 8; ++j) Bs[(c8 * 8 + j) * 40 + r] = (bf16)vals[j];
    }
    __syncthreads();

    bf16x8 af[4], bfr[4];
#pragma unroll
    for (int mi = 0; mi < 4; ++mi)
      af[mi] = *(const bf16x8*)&As[(wr * 64 + mi * 16 + ln) * 40 + hi * 8];
#pragma unroll
    for (int ni = 0; ni < 4; ++ni)
      bfr[ni] = *(const bf16x8*)&Bs[(wc * 64 + ni * 16 + ln) * 40 + hi * 8];
#pragma unroll
    for (int mi = 0; mi < 4; ++mi)
#pragma unroll
      for (int ni = 0; ni < 4; ++ni)
        acc[mi][ni] = __builtin_amdgcn_mfma_f32_16x16x32_bf16(af[mi], bfr[ni], acc[mi][ni], 0, 0, 0);
  }

  // D: col = lane&15, row = (lane>>4)*4 + reg
#pragma unroll
  for (int mi = 0; mi < 4; ++mi) {
    int rowb = m0 + wr * 64 + mi * 16 + hi * 4;
    int b = rowb >> 12, t0 = rowb & 4095;
#pragma unroll
    for (int ni = 0; ni < 4; ++ni) {
      int n = n0 + wc * 64 + ni * 16 + ln;
      int which = n >> 9, c = n & 511, h = c >> 6, d = c & 63;
      if (which == 2) {
        // v -> [bh][d][t], 4 consecutive t => one 8B store
        bf16x4 pv;
#pragma unroll
        for (int r = 0; r < 4; ++r) pv[r] = (bf16)acc[mi][ni][r];
        *(bf16x4*)&vw[((size_t)(b * HH + h) * HD + d) * TT + t0] = pv;
      } else {
        bf16* dst = which ? kw : qw;
#pragma unroll
        for (int r = 0; r < 4; ++r)
          dst[((size_t)(b * HH + h) * TT + t0 + r) * HD + d] = (bf16)acc[mi][ni][r];
      }
    }
  }
}

// ---------------------------------------------------------------------------
// Flash attention, causal. 1D grid 512 (work-paired). 4 waves x 32 q-rows.
// Swapped QK^T (D col = q = ln) -> lane-local softmax rows; P stays in
// registers; PV uses pi-permuted V fragments (ds_read_b64 pairs) so no
// cross-lane P redistribution is needed. K/V double-buffered, 1 barrier/tile.
// ---------------------------------------------------------------------------
__global__ __launch_bounds__(256) void attn_kernel(
    const bf16* __restrict__ qw, const bf16* __restrict__ kw,
    const bf16* __restrict__ vt, bf16* __restrict__ aw) {
  __shared__ __align__(16) bf16 Ks[2][64 * 64];
  __shared__ __align__(16) bf16 Vs[2][64 * 64];     // [d][kv]
  const int tid = threadIdx.x;
  const int wid = tid >> 6, lane = tid & 63, ln = lane & 15, hi = lane >> 4;

  // pair blocks: half 0 -> qb = p, half 1 -> qb = 31-p (constant work per pair)
  const int bid = blockIdx.x;
  const int half = bid >> 8, rem = bid & 255;
  const int bh = rem >> 4, p = rem & 15;
  const int qb = half ? (31 - p) : p;
  const int q0w = qb * 128 + wid * 32;

  const float SCL = 0.125f * 1.44269504f;   // exp2 domain

  // Q fragments: row/col = ln, k = h*32 + hi*8 + j  (works as A- or B-frag)
  bf16x8 qf[2][2];
#pragma unroll
  for (int qi = 0; qi < 2; ++qi)
#pragma unroll
    for (int h = 0; h < 2; ++h)
      qf[qi][h] = *(const bf16x8*)&qw[((size_t)bh * TT + q0w + qi * 16 + ln) * HD + h * 32 + hi * 8];

  f32x4 o[2][4] = {};
  float mrow[2] = {-1e30f, -1e30f}, lrow[2] = {0.f, 0.f};

  const int ntiles = 2 * (qb + 1);
  const int r0 = tid >> 3, c0 = tid & 7;    // staging row/chunk
  const int sc = (c0 ^ (r0 & 7)) * 8;       // swizzled chunk (r0+32 same)
  const size_t kb = (size_t)bh * TT * HD, vb = (size_t)bh * HD * TT;

  bf16x8 pre[4];
  // tile 0
  pre[0] = *(const bf16x8*)&kw[kb + (size_t)r0 * HD + c0 * 8];
  pre[1] = *(const bf16x8*)&kw[kb + (size_t)(r0 + 32) * HD + c0 * 8];
  pre[2] = *(const bf16x8*)&vt[vb + (size_t)r0 * TT + c0 * 8];
  pre[3] = *(const bf16x8*)&vt[vb + (size_t)(r0 + 32) * TT + c0 * 8];
  *(bf16x8*)&Ks[0][r0 * 64 + sc] = pre[0];
  *(bf16x8*)&Ks[0][(r0 + 32) * 64 + sc] = pre[1];
  *(bf16x8*)&Vs[0][r0 * 64 + sc] = pre[2];
  *(bf16x8*)&Vs[0][(r0 + 32) * 64 + sc] = pre[3];
  // issue tile 1 (ntiles >= 2 always)
  pre[0] = *(const bf16x8*)&kw[kb + (size_t)(64 + r0) * HD + c0 * 8];
  pre[1] = *(const bf16x8*)&kw[kb + (size_t)(64 + r0 + 32) * HD + c0 * 8];
  pre[2] = *(const bf16x8*)&vt[vb + (size_t)r0 * TT + 64 + c0 * 8];
  pre[3] = *(const bf16x8*)&vt[vb + (size_t)(r0 + 32) * TT + 64 + c0 * 8];
  __syncthreads();

  for (int t = 0; t < ntiles; ++t) {
    const int kv0 = t * 64;
    const int buf = t & 1;
    if (kv0 <= q0w + 31) {
      // ---- QK^T swapped: D[kv][q], col=ln=q, row=hi*4+r = kv within kt tile
      f32x4 s[2][4];
#pragma unroll
      for (int kt = 0; kt < 4; ++kt) {
        const int krow = kt * 16 + ln;
        const bf16* kbase = &Ks[buf][krow * 64];
        bf16x8 kf0 = *(const bf16x8*)&kbase[(hi ^ (krow & 7)) * 8];
        bf16x8 kf1 = *(const bf16x8*)&kbase[((4 + hi) ^ (krow & 7)) * 8];
#pragma unroll
        for (int qi = 0; qi < 2; ++qi) {
          f32x4 a = {};
          a = __builtin_amdgcn_mfma_f32_16x16x32_bf16(kf0, qf[qi][0], a, 0, 0, 0);
          a = __builtin_amdgcn_mfma_f32_16x16x32_bf16(kf1, qf[qi][1], a, 0, 0, 0);
          s[qi][kt] = a * SCL;
        }
      }
      // ---- causal mask: q = q0w+qi*16+ln, kv = kv0+kt*16+hi*4+r
#pragma unroll
      for (int qi = 0; qi < 2; ++qi) {
        if (kv0 + 63 > q0w + qi * 16) {
          const int qg = q0w + qi * 16 + ln;
#pragma unroll
          for (int kt = 0; kt < 4; ++kt)
#pragma unroll
            for (int r = 0; r < 4; ++r)
              if (kv0 + kt * 16 + hi * 4 + r > qg) s[qi][kt][r] = -1e30f;
        }
      }
      // ---- online softmax: each lane owns row q = q0w+qi*16+ln
      bf16x8 pa[2][2];
#pragma unroll
      for (int qi = 0; qi < 2; ++qi) {
        float v = s[qi][0][0];
#pragma unroll
        for (int kt = 0; kt < 4; ++kt)
#pragma unroll
          for (int r = 0; r < 4; ++r) v = fmaxf(v, s[qi][kt][r]);
        v = fmaxf(v, __shfl_xor(v, 16));
        v = fmaxf(v, __shfl_xor(v, 32));
        const float mn = fmaxf(mrow[qi], v);
        const float al = exp2f(mrow[qi] - mn);
        mrow[qi] = mn;
        float rs = 0.f;
#pragma unroll
        for (int kt = 0; kt < 4; ++kt)
#pragma unroll
          for (int r = 0; r < 4; ++r) {
            float pv = exp2f(s[qi][kt][r] - mn);
            s[qi][kt][r] = pv;
            rs += pv;
          }
        rs += __shfl_xor(rs, 16);
        rs += __shfl_xor(rs, 32);
        lrow[qi] = lrow[qi] * al + rs;
        // broadcast alpha from ln-space to (hi*4+r)-space, rescale O
        float ar[4];
#pragma unroll
        for (int r = 0; r < 4; ++r) ar[r] = __shfl(al, hi * 4 + r);
#pragma unroll
        for (int db = 0; db < 4; ++db)
#pragma unroll
          for (int r = 0; r < 4; ++r) o[qi][db][r] *= ar[r];
        // pack P to A-frag: slot j of half h2 -> kv = 32*h2 + 16*(j>>2) + 4*hi + (j&3)
#pragma unroll
        for (int h2 = 0; h2 < 2; ++h2)
#pragma unroll
          for (int j = 0; j < 8; ++j)
            pa[qi][h2][j] = (bf16)s[qi][h2 * 2 + (j >> 2)][j & 3];
      }
      // ---- PV with pi-permuted V fragments: B slot j of half h2 must hold
      //      V[kv0 + 32*h2 + 16*(j>>2) + 4*hi + (j&3)][d]
      const bf16* vbase = Vs[buf];
#pragma unroll
      for (int db = 0; db < 4; ++db) {
        const int d = db * 16 + ln, rowb = d * 64, dx = d & 7;
#pragma unroll
        for (int h2 = 0; h2 < 2; ++h2) {
          const int c1 = h2 * 4 + (hi >> 1);        // 16B chunk of kv 32*h2+4*hi
          bf16x4 lo = *(const bf16x4*)&vbase[rowb + ((c1 ^ dx) * 8) + (hi & 1) * 4];
          bf16x4 hi4 = *(const bf16x4*)&vbase[rowb + (((c1 + 2) ^ dx) * 8) + (hi & 1) * 4];
          bf16x8 vf = __builtin_shufflevector(lo, hi4, 0, 1, 2, 3, 4, 5, 6, 7);
#pragma unroll
          for (int qi = 0; qi < 2; ++qi)
            o[qi][db] = __builtin_amdgcn_mfma_f32_16x16x32_bf16(pa[qi][h2], vf, o[qi][db], 0, 0, 0);
        }
      }
    }
    // ---- stage next tile into other buffer; issue loads for tile t+2
    if (t + 1 < ntiles) {
      const int nbuf = buf ^ 1;
      *(bf16x8*)&Ks[nbuf][r0 * 64 + sc] = pre[0];
      *(bf16x8*)&Ks[nbuf][(r0 + 32) * 64 + sc] = pre[1];
      *(bf16x8*)&Vs[nbuf][r0 * 64 + sc] = pre[2];
      *(bf16x8*)&Vs[nbuf][(r0 + 32) * 64 + sc] = pre[3];
      if (t + 2 < ntiles) {
        const int kv2 = kv0 + 128;
        pre[0] = *(const bf16x8*)&kw[kb + (size_t)(kv2 + r0) * HD + c0 * 8];
        pre[1] = *(const bf16x8*)&kw[kb + (size_t)(kv2 + r0 + 32) * HD + c0 * 8];
        pre[2] = *(const bf16x8*)&vt[vb + (size_t)r0 * TT + kv2 + c0 * 8];
        pre[3] = *(const bf16x8*)&vt[vb + (size_t)(r0 + 32) * TT + kv2 + c0 * 8];
      }
    }
    __syncthreads();
  }

  // ---- epilogue: divide by lrow (broadcast ln-space -> row-space), store
#pragma unroll
  for (int qi = 0; qi < 2; ++qi) {
    const float inv = 1.0f / lrow[qi];
    float ir[4];
#pragma unroll
    for (int r = 0; r < 4; ++r) ir[r] = __shfl(inv, hi * 4 + r);
#pragma unroll
    for (int db = 0; db < 4; ++db)
#pragma unroll
      for (int r = 0; r < 4; ++r) {
        int q = q0w + qi * 16 + hi * 4 + r;
        aw[((size_t)bh * TT + q) * HD + db * 16 + ln] = (bf16)(o[qi][db][r] * ir[r]);
      }
  }
}

// ---------------------------------------------------------------------------
// GEMM 3: out = attn @ w_out   [8192,512] x [512,512] -> f32 out
// ---------------------------------------------------------------------------
__global__ __launch_bounds__(256) void gemm_out_kernel(
    const bf16* __restrict__ A, const float* __restrict__ W,
    float* __restrict__ out) {
  __shared__ __align__(16) bf16 As[128 * 40];
  __shared__ __align__(16) bf16 Bs[128 * 40];
  const int tid = threadIdx.x;
  const int wid = tid >> 6, lane = tid & 63, ln = lane & 15, hi = lane >> 4;
  const int wr = wid >> 1, wc = wid & 1;
  const int m0 = blockIdx.x * 128, n0 = blockIdx.y * 128;

  f32x4 acc[4][4] = {};

  for (int k0 = 0; k0 < 512; k0 += 32) {
    __syncthreads();
#pragma unroll
    for (int it = 0; it < 2; ++it) {
      int ch = tid + it * 256;
      int r = ch >> 2, c8 = ch & 3;
      int m = m0 + r, k = k0 + c8 * 8;
      int b = m >> 12, t = m & 4095, h = k >> 6, d = k & 63;
      *(bf16x8*)&As[r * 40 + c8 * 8] =
          *(const bf16x8*)&A[((size_t)(b * HH + h) * TT + t) * HD + d];
    }
#pragma unroll
    for (int it = 0; it < 2; ++it) {
      int ch = tid + it * 256;
      int r = ch >> 4, c8 = ch & 15;
      const float4* p = (const float4*)(W + (size_t)(k0 + r) * 512 + n0 + c8 * 8);
      float4 a = p[0], b = p[1];
      float vals[8] = {a.x, a.y, a.z, a.w, b.x, b.y, b.z, b.w};
#pragma unroll
      for (int j = 0; j < 8; ++j) Bs[(c8 * 8 + j) * 40 + r] = (bf16)vals[j];
    }
    __syncthreads();

    bf16x8 af[4], bfr[4];
#pragma unroll
    for (int mi = 0; mi < 4; ++mi)
      af[mi] = *(const bf16x8*)&As[(wr * 64 + mi * 16 + ln) * 40 + hi * 8];
#pragma unroll
    for (int ni = 0; ni < 4; ++ni)
      bfr[ni] = *(const bf16x8*)&Bs[(wc * 64 + ni * 16 + ln) * 40 + hi * 8];
#pragma unroll
    for (int mi = 0; mi < 4; ++mi)
#pragma unroll
      for (int ni = 0; ni < 4; ++ni)
        acc[mi][ni] = __builtin_amdgcn_mfma_f32_16x16x32_bf16(af[mi], bfr[ni], acc[mi][ni], 0, 0, 0);
  }

#pragma unroll
  for (int mi = 0; mi < 4; ++mi) {
    int rowb = m0 + wr * 64 + mi * 16 + hi * 4;
#pragma unroll
    for (int ni = 0; ni < 4; ++ni) {
      int n = n0 + wc * 64 + ni * 16 + ln;
#pragma unroll
      for (int r = 0; r < 4; ++r)
        out[(size_t)(rowb + r) * 512 + n] = acc[mi][ni][r];
    }
  }
}

extern "C" void kernel_launch(void* const* d_in, const int* in_sizes, int n_in,
                              void* d_out, int out_size, void* d_ws, size_t ws_size,
                              hipStream_t stream) {
  const float* x = (const float*)d_in[0];
  const float* w_qkv = (const float*)d_in[1];
  const float* w_out = (const float*)d_in[2];
  float* out = (float*)d_out;

  const size_t QKV_ELEMS = (size_t)BHD * TT * HD;   // 4,194,304
  bf16* qw = (bf16*)d_ws;
  bf16* kw = qw + QKV_ELEMS;
  bf16* vw = kw + QKV_ELEMS;   // transposed layout [bh][d][t]
  bf16* aw = vw + QKV_ELEMS;

  gemm_qkv_kernel<<<dim3(M_TOT / 128, 1536 / 128), 256, 0, stream>>>(x, w_qkv, qw, kw, vw);
  attn_kernel<<<512, 256, 0, stream>>>(qw, kw, vw, aw);
  gemm_out_kernel<<<dim3(M_TOT / 128, 512 / 128), 256, 0, stream>>>(aw, w_out, out);
}

// Round 4
// 181.364 us; speedup vs baseline: 2.2605x; 1.1958x over previous
//
#include <hip/hip_runtime.h>
#include <hip/hip_bf16.h>

typedef __bf16 bf16;
typedef __bf16 bf16x4 __attribute__((ext_vector_type(4)));
typedef __bf16 bf16x8 __attribute__((ext_vector_type(8)));
typedef float f32x4 __attribute__((ext_vector_type(4)));

// Problem constants
#define BB 2
#define TT 4096
#define CC 512
#define HH 8
#define HD 64
#define BHD 16          // B*H
#define M_TOT 8192      // B*T

// ---------------------------------------------------------------------------
// GEMM 1: qkv = x @ w_qkv   [8192,512] x [512,1536] -> scatter q/k bf16
// [bh][t][d]; v transposed to [bh][d][t] for conflict-free attn staging.
// ---------------------------------------------------------------------------
__global__ __launch_bounds__(256) void gemm_qkv_kernel(
    const float* __restrict__ X, const float* __restrict__ W,
    bf16* __restrict__ qw, bf16* __restrict__ kw, bf16* __restrict__ vw) {
  __shared__ __align__(16) bf16 As[128 * 40];
  __shared__ __align__(16) bf16 Bs[128 * 40];   // transposed: [n][k]
  const int tid = threadIdx.x;
  const int wid = tid >> 6, lane = tid & 63, ln = lane & 15, hi = lane >> 4;
  const int wr = wid >> 1, wc = wid & 1;
  const int m0 = blockIdx.x * 128, n0 = blockIdx.y * 128;

  f32x4 acc[4][4] = {};

  for (int k0 = 0; k0 < 512; k0 += 32) {
    __syncthreads();
#pragma unroll
    for (int it = 0; it < 2; ++it) {
      int ch = tid + it * 256;          // 512 chunks of 8
      int r = ch >> 2, c8 = ch & 3;
      const float4* p = (const float4*)(X + (size_t)(m0 + r) * 512 + k0 + c8 * 8);
      float4 a = p[0], b = p[1];
      bf16x8 v;
      v[0] = (bf16)a.x; v[1] = (bf16)a.y; v[2] = (bf16)a.z; v[3] = (bf16)a.w;
      v[4] = (bf16)b.x; v[5] = (bf16)b.y; v[6] = (bf16)b.z; v[7] = (bf16)b.w;
      *(bf16x8*)&As[r * 40 + c8 * 8] = v;
    }
#pragma unroll
    for (int it = 0; it < 2; ++it) {
      int ch = tid + it * 256;          // 32 rows x 16 chunks
      int r = ch >> 4, c8 = ch & 15;
      const float4* p = (const float4*)(W + (size_t)(k0 + r) * 1536 + n0 + c8 * 8);
      float4 a = p[0], b = p[1];
      float vals[8] = {a.x, a.y, a.z, a.w, b.x, b.y, b.z, b.w};
#pragma unroll
      for (int j = 0; j < 8; ++j) Bs[(c8 * 8 + j) * 40 + r] = (bf16)vals[j];
    }
    __syncthreads();

    bf16x8 af[4], bfr[4];
#pragma unroll
    for (int mi = 0; mi < 4; ++mi)
      af[mi] = *(const bf16x8*)&As[(wr * 64 + mi * 16 + ln) * 40 + hi * 8];
#pragma unroll
    for (int ni = 0; ni < 4; ++ni)
      bfr[ni] = *(const bf16x8*)&Bs[(wc * 64 + ni * 16 + ln) * 40 + hi * 8];
#pragma unroll
    for (int mi = 0; mi < 4; ++mi)
#pragma unroll
      for (int ni = 0; ni < 4; ++ni)
        acc[mi][ni] = __builtin_amdgcn_mfma_f32_16x16x32_bf16(af[mi], bfr[ni], acc[mi][ni], 0, 0, 0);
  }

  // D: col = lane&15, row = (lane>>4)*4 + reg
#pragma unroll
  for (int mi = 0; mi < 4; ++mi) {
    int rowb = m0 + wr * 64 + mi * 16 + hi * 4;
    int b = rowb >> 12, t0 = rowb & 4095;
#pragma unroll
    for (int ni = 0; ni < 4; ++ni) {
      int n = n0 + wc * 64 + ni * 16 + ln;
      int which = n >> 9, c = n & 511, h = c >> 6, d = c & 63;
      if (which == 2) {
        // v -> [bh][d][t], 4 consecutive t => one 8B store
        bf16x4 pv;
#pragma unroll
        for (int r = 0; r < 4; ++r) pv[r] = (bf16)acc[mi][ni][r];
        *(bf16x4*)&vw[((size_t)(b * HH + h) * HD + d) * TT + t0] = pv;
      } else {
        bf16* dst = which ? kw : qw;
#pragma unroll
        for (int r = 0; r < 4; ++r)
          dst[((size_t)(b * HH + h) * TT + t0 + r) * HD + d] = (bf16)acc[mi][ni][r];
      }
    }
  }
}

// ---------------------------------------------------------------------------
// Flash attention, causal. grid 1024 = 64 qb x 16 bh, heavy-first.
// 4 waves x 16 q-rows (QBLK=64). Swapped QK^T -> lane-local softmax rows;
// P in registers; pi-permuted V fragments; K/V double-buffered; defer-max.
// ---------------------------------------------------------------------------
__global__ __launch_bounds__(256) void attn_kernel(
    const bf16* __restrict__ qw, const bf16* __restrict__ kw,
    const bf16* __restrict__ vt, bf16* __restrict__ aw) {
  __shared__ __align__(16) bf16 Ks[2][64 * 64];
  __shared__ __align__(16) bf16 Vs[2][64 * 64];     // [d][kv]
  const int tid = threadIdx.x;
  const int wid = tid >> 6, lane = tid & 63, ln = lane & 15, hi = lane >> 4;

  const int bid = blockIdx.x;
  const int qb = 63 - (bid >> 4);       // heavy blocks dispatched first
  const int bh = bid & 15;
  const int q0w = qb * 64 + wid * 16;

  const float SCL = 0.125f * 1.44269504f;   // exp2 domain

  // Q fragment: row/col = ln, k = h*32 + hi*8 + j
  bf16x8 qf[2];
#pragma unroll
  for (int h = 0; h < 2; ++h)
    qf[h] = *(const bf16x8*)&qw[((size_t)bh * TT + q0w + ln) * HD + h * 32 + hi * 8];

  f32x4 o[4] = {};
  float mrow = -1e30f, lrow = 0.f;

  const int ntiles = qb + 1;
  const int r0 = tid >> 3, c0 = tid & 7;    // staging row/chunk
  const int sc = (c0 ^ (r0 & 7)) * 8;       // swizzled chunk (r0+32 same)
  const size_t kb = (size_t)bh * TT * HD, vb = (size_t)bh * HD * TT;

  bf16x8 pre[4];
  // tile 0
  pre[0] = *(const bf16x8*)&kw[kb + (size_t)r0 * HD + c0 * 8];
  pre[1] = *(const bf16x8*)&kw[kb + (size_t)(r0 + 32) * HD + c0 * 8];
  pre[2] = *(const bf16x8*)&vt[vb + (size_t)r0 * TT + c0 * 8];
  pre[3] = *(const bf16x8*)&vt[vb + (size_t)(r0 + 32) * TT + c0 * 8];
  *(bf16x8*)&Ks[0][r0 * 64 + sc] = pre[0];
  *(bf16x8*)&Ks[0][(r0 + 32) * 64 + sc] = pre[1];
  *(bf16x8*)&Vs[0][r0 * 64 + sc] = pre[2];
  *(bf16x8*)&Vs[0][(r0 + 32) * 64 + sc] = pre[3];
  if (ntiles > 1) {   // issue tile 1
    pre[0] = *(const bf16x8*)&kw[kb + (size_t)(64 + r0) * HD + c0 * 8];
    pre[1] = *(const bf16x8*)&kw[kb + (size_t)(64 + r0 + 32) * HD + c0 * 8];
    pre[2] = *(const bf16x8*)&vt[vb + (size_t)r0 * TT + 64 + c0 * 8];
    pre[3] = *(const bf16x8*)&vt[vb + (size_t)(r0 + 32) * TT + 64 + c0 * 8];
  }
  __syncthreads();

  for (int t = 0; t < ntiles; ++t) {
    const int kv0 = t * 64;
    const int buf = t & 1;

    // ---- QK^T swapped: D[kv][q], col=ln=q, row=hi*4+r = kv within kt tile
    f32x4 s[4];
    __builtin_amdgcn_s_setprio(1);
#pragma unroll
    for (int kt = 0; kt < 4; ++kt) {
      const int krow = kt * 16 + ln;
      const bf16* kbase = &Ks[buf][krow * 64];
      bf16x8 kf0 = *(const bf16x8*)&kbase[(hi ^ (krow & 7)) * 8];
      bf16x8 kf1 = *(const bf16x8*)&kbase[((4 + hi) ^ (krow & 7)) * 8];
      f32x4 a = {};
      a = __builtin_amdgcn_mfma_f32_16x16x32_bf16(kf0, qf[0], a, 0, 0, 0);
      a = __builtin_amdgcn_mfma_f32_16x16x32_bf16(kf1, qf[1], a, 0, 0, 0);
      s[kt] = a * SCL;
    }
    __builtin_amdgcn_s_setprio(0);

    // ---- causal mask: only the diagonal tile needs it
    if (t == qb) {
      const int qg = q0w + ln;
#pragma unroll
      for (int kt = 0; kt < 4; ++kt)
#pragma unroll
        for (int r = 0; r < 4; ++r)
          if (kv0 + kt * 16 + hi * 4 + r > qg) s[kt][r] = -1e30f;
    }

    // ---- online softmax with defer-max: lane owns row q = q0w + ln
    float pmax = s[0][0];
#pragma unroll
    for (int kt = 0; kt < 4; ++kt)
#pragma unroll
      for (int r = 0; r < 4; ++r) pmax = fmaxf(pmax, s[kt][r]);
    pmax = fmaxf(pmax, __shfl_xor(pmax, 16));
    pmax = fmaxf(pmax, __shfl_xor(pmax, 32));
    if (!__all(pmax <= mrow + 8.f)) {
      const float mn = fmaxf(mrow, pmax);
      const float al = exp2f(mrow - mn);
      mrow = mn;
      lrow *= al;
      float ar[4];
#pragma unroll
      for (int r = 0; r < 4; ++r) ar[r] = __shfl(al, hi * 4 + r);
#pragma unroll
      for (int db = 0; db < 4; ++db)
#pragma unroll
        for (int r = 0; r < 4; ++r) o[db][r] *= ar[r];
    }
    float rs = 0.f;
#pragma unroll
    for (int kt = 0; kt < 4; ++kt)
#pragma unroll
      for (int r = 0; r < 4; ++r) {
        float pv = exp2f(s[kt][r] - mrow);
        s[kt][r] = pv;
        rs += pv;
      }
    rs += __shfl_xor(rs, 16);
    rs += __shfl_xor(rs, 32);
    lrow += rs;
    // pack P to A-frag: slot j of half h2 -> kv = 32*h2 + 16*(j>>2) + 4*hi + (j&3)
    bf16x8 pa[2];
#pragma unroll
    for (int h2 = 0; h2 < 2; ++h2)
#pragma unroll
      for (int j = 0; j < 8; ++j)
        pa[h2][j] = (bf16)s[h2 * 2 + (j >> 2)][j & 3];

    // ---- PV with pi-permuted V fragments
    const bf16* vbase = Vs[buf];
    __builtin_amdgcn_s_setprio(1);
#pragma unroll
    for (int db = 0; db < 4; ++db) {
      const int d = db * 16 + ln, rowb = d * 64, dx = d & 7;
#pragma unroll
      for (int h2 = 0; h2 < 2; ++h2) {
        const int c1 = h2 * 4 + (hi >> 1);        // 16B chunk of kv 32*h2+4*hi
        bf16x4 lo = *(const bf16x4*)&vbase[rowb + ((c1 ^ dx) * 8) + (hi & 1) * 4];
        bf16x4 hi4 = *(const bf16x4*)&vbase[rowb + (((c1 + 2) ^ dx) * 8) + (hi & 1) * 4];
        bf16x8 vf = __builtin_shufflevector(lo, hi4, 0, 1, 2, 3, 4, 5, 6, 7);
        o[db] = __builtin_amdgcn_mfma_f32_16x16x32_bf16(pa[h2], vf, o[db], 0, 0, 0);
      }
    }
    __builtin_amdgcn_s_setprio(0);

    // ---- stage next tile into other buffer; issue loads for tile t+2
    if (t + 1 < ntiles) {
      const int nbuf = buf ^ 1;
      *(bf16x8*)&Ks[nbuf][r0 * 64 + sc] = pre[0];
      *(bf16x8*)&Ks[nbuf][(r0 + 32) * 64 + sc] = pre[1];
      *(bf16x8*)&Vs[nbuf][r0 * 64 + sc] = pre[2];
      *(bf16x8*)&Vs[nbuf][(r0 + 32) * 64 + sc] = pre[3];
      if (t + 2 < ntiles) {
        const int kv2 = kv0 + 128;
        pre[0] = *(const bf16x8*)&kw[kb + (size_t)(kv2 + r0) * HD + c0 * 8];
        pre[1] = *(const bf16x8*)&kw[kb + (size_t)(kv2 + r0 + 32) * HD + c0 * 8];
        pre[2] = *(const bf16x8*)&vt[vb + (size_t)r0 * TT + kv2 + c0 * 8];
        pre[3] = *(const bf16x8*)&vt[vb + (size_t)(r0 + 32) * TT + kv2 + c0 * 8];
      }
    }
    __syncthreads();
  }

  // ---- epilogue: divide by lrow (broadcast ln-space -> row-space), store
  {
    const float inv = 1.0f / lrow;
    float ir[4];
#pragma unroll
    for (int r = 0; r < 4; ++r) ir[r] = __shfl(inv, hi * 4 + r);
#pragma unroll
    for (int db = 0; db < 4; ++db)
#pragma unroll
      for (int r = 0; r < 4; ++r) {
        int q = q0w + hi * 4 + r;
        aw[((size_t)bh * TT + q) * HD + db * 16 + ln] = (bf16)(o[db][r] * ir[r]);
      }
  }
}

// ---------------------------------------------------------------------------
// GEMM 3: out = attn @ w_out   [8192,512] x [512,512] -> f32 out
// ---------------------------------------------------------------------------
__global__ __launch_bounds__(256) void gemm_out_kernel(
    const bf16* __restrict__ A, const float* __restrict__ W,
    float* __restrict__ out) {
  __shared__ __align__(16) bf16 As[128 * 40];
  __shared__ __align__(16) bf16 Bs[128 * 40];
  const int tid = threadIdx.x;
  const int wid = tid >> 6, lane = tid & 63, ln = lane & 15, hi = lane >> 4;
  const int wr = wid >> 1, wc = wid & 1;
  const int m0 = blockIdx.x * 128, n0 = blockIdx.y * 128;

  f32x4 acc[4][4] = {};

  for (int k0 = 0; k0 < 512; k0 += 32) {
    __syncthreads();
#pragma unroll
    for (int it = 0; it < 2; ++it) {
      int ch = tid + it * 256;
      int r = ch >> 2, c8 = ch & 3;
      int m = m0 + r, k = k0 + c8 * 8;
      int b = m >> 12, t = m & 4095, h = k >> 6, d = k & 63;
      *(bf16x8*)&As[r * 40 + c8 * 8] =
          *(const bf16x8*)&A[((size_t)(b * HH + h) * TT + t) * HD + d];
    }
#pragma unroll
    for (int it = 0; it < 2; ++it) {
      int ch = tid + it * 256;
      int r = ch >> 4, c8 = ch & 15;
      const float4* p = (const float4*)(W + (size_t)(k0 + r) * 512 + n0 + c8 * 8);
      float4 a = p[0], b = p[1];
      float vals[8] = {a.x, a.y, a.z, a.w, b.x, b.y, b.z, b.w};
#pragma unroll
      for (int j = 0; j < 8; ++j) Bs[(c8 * 8 + j) * 40 + r] = (bf16)vals[j];
    }
    __syncthreads();

    bf16x8 af[4], bfr[4];
#pragma unroll
    for (int mi = 0; mi < 4; ++mi)
      af[mi] = *(const bf16x8*)&As[(wr * 64 + mi * 16 + ln) * 40 + hi * 8];
#pragma unroll
    for (int ni = 0; ni < 4; ++ni)
      bfr[ni] = *(const bf16x8*)&Bs[(wc * 64 + ni * 16 + ln) * 40 + hi * 8];
#pragma unroll
    for (int mi = 0; mi < 4; ++mi)
#pragma unroll
      for (int ni = 0; ni < 4; ++ni)
        acc[mi][ni] = __builtin_amdgcn_mfma_f32_16x16x32_bf16(af[mi], bfr[ni], acc[mi][ni], 0, 0, 0);
  }

#pragma unroll
  for (int mi = 0; mi < 4; ++mi) {
    int rowb = m0 + wr * 64 + mi * 16 + hi * 4;
#pragma unroll
    for (int ni = 0; ni < 4; ++ni) {
      int n = n0 + wc * 64 + ni * 16 + ln;
#pragma unroll
      for (int r = 0; r < 4; ++r)
        out[(size_t)(rowb + r) * 512 + n] = acc[mi][ni][r];
    }
  }
}

extern "C" void kernel_launch(void* const* d_in, const int* in_sizes, int n_in,
                              void* d_out, int out_size, void* d_ws, size_t ws_size,
                              hipStream_t stream) {
  const float* x = (const float*)d_in[0];
  const float* w_qkv = (const float*)d_in[1];
  const float* w_out = (const float*)d_in[2];
  float* out = (float*)d_out;

  const size_t QKV_ELEMS = (size_t)BHD * TT * HD;   // 4,194,304
  bf16* qw = (bf16*)d_ws;
  bf16* kw = qw + QKV_ELEMS;
  bf16* vw = kw + QKV_ELEMS;   // transposed layout [bh][d][t]
  bf16* aw = vw + QKV_ELEMS;

  gemm_qkv_kernel<<<dim3(M_TOT / 128, 1536 / 128), 256, 0, stream>>>(x, w_qkv, qw, kw, vw);
  attn_kernel<<<1024, 256, 0, stream>>>(qw, kw, vw, aw);
  gemm_out_kernel<<<dim3(M_TOT / 128, 512 / 128), 256, 0, stream>>>(aw, w_out, out);
}